// Round 1
// baseline (434.671 us; speedup 1.0000x reference)
//
#include <hip/hip_runtime.h>
#include <math.h>

// SPDNet: x[4096,64,256] -> cov -> BiMap(W) -> ReEig -> LogEig -> Linear(Wc,bc) -> log_softmax
// Strategy: Y = (Wt x)(Wt x)^T/T - m m^T  (32x32 SPD, spectrum in ~[0.15,2.6]);
// log(Y) contracted with Wc via Chebyshev matrix recurrence, closed-form coeffs.

#define C_CH 64
#define T_LEN 256
#define NCH 32      // highest Chebyshev degree
#define LSTR 40     // LDS row stride (floats) for 32x32 buffers

// ---------------- Kernel A: Y[b] = W^T cov(x[b]) W ----------------
__global__ __launch_bounds__(256) void spd_stage1(
    const float* __restrict__ x, const float* __restrict__ W,
    float* __restrict__ Yout)
{
  __shared__ __align__(16) float V[32 * 260];   // V rows padded: 260 floats
  __shared__ float psum[32 * 8];
  __shared__ float msh[32];

  const int b = blockIdx.x;
  const int t = threadIdx.x;            // 0..255 = time column
  const float* xb = x + (size_t)b * (C_CH * T_LEN);

  // V_raw[d][t] = sum_c W[c][d] * x[b][c][t]   (W index uniform -> s_load)
  float acc[32];
#pragma unroll
  for (int d = 0; d < 32; ++d) acc[d] = 0.f;

  for (int c = 0; c < C_CH; ++c) {
    const float xv = xb[c * T_LEN + t];
    const float* wr = &W[c * 32];
#pragma unroll
    for (int d = 0; d < 32; ++d) acc[d] = fmaf(wr[d], xv, acc[d]);
  }
#pragma unroll
  for (int d = 0; d < 32; ++d) V[d * 260 + t] = acc[d];
  __syncthreads();

  // row partial sums -> means
  {
    const int d = t >> 3, seg = t & 7;
    const float* vr = &V[d * 260 + seg * 32];
    float s = 0.f;
#pragma unroll
    for (int u = 0; u < 32; ++u) s += vr[u];
    psum[d * 8 + seg] = s;
  }
  __syncthreads();
  if (t < 32) {
    float s = 0.f;
#pragma unroll
    for (int g = 0; g < 8; ++g) s += psum[t * 8 + g];
    msh[t] = s * (1.f / 256.f);
  }
  __syncthreads();

  // 528 upper-triangle dots: Y[i][j] = dot(Vi,Vj)/T - m_i m_j
  float* Yb = Yout + (size_t)b * 1024;
  for (int pi = t; pi < 528; pi += 256) {
    int i = 0;
    while (i < 31) {
      int nb = (i + 1) * 32 - ((i + 1) * i) / 2;   // base(i+1)
      if (pi < nb) break;
      ++i;
    }
    const int base = i * 32 - (i * (i - 1)) / 2;
    const int j = i + (pi - base);
    const float4* va = (const float4*)&V[i * 260];
    const float4* vb = (const float4*)&V[j * 260];
    float sx = 0.f, sy = 0.f, sz = 0.f, sw = 0.f;
#pragma unroll 8
    for (int qq = 0; qq < 64; ++qq) {
      float4 A4 = va[qq], B4 = vb[qq];
      sx = fmaf(A4.x, B4.x, sx);
      sy = fmaf(A4.y, B4.y, sy);
      sz = fmaf(A4.z, B4.z, sz);
      sw = fmaf(A4.w, B4.w, sw);
    }
    const float s = (sx + sy) + (sz + sw);
    const float yv = s * (1.f / 256.f) - msh[i] * msh[j];
    Yb[i * 32 + j] = yv;
    Yb[j * 32 + i] = yv;
  }
}

// ------- Kernel B: logits_o = sum_k c_k <M_o, T_k(Yhat)>, log_softmax -------
__global__ __launch_bounds__(64) void spd_cheb(
    const float* __restrict__ Yws, const float* __restrict__ Wc,
    const float* __restrict__ bcv, float* __restrict__ out)
{
  __shared__ __align__(16) float Bs[2][32 * LSTR];

  const int b = blockIdx.x, l = threadIdx.x;
  const int i0 = (l >> 2) * 2;        // lane's output rows i0, i0+1
  const int j0 = (l & 3) * 8;         // lane's output cols j0..j0+7

  const float lo = 0.08f, hi = 3.0f;
  const float p = 0.5f * (hi + lo), q = 0.5f * (hi - lo), invq = 1.f / q;
  const float rr = -(p - sqrtf(lo * hi)) * invq;   // ~ -0.719
  const float c0 = logf(p / (1.f + rr * rr));

  const float* Yb = Yws + (size_t)b * 1024;

  // Yhat rows i0, i0+1 in registers (fully const-indexed)
  float y0[32], y1[32];
#pragma unroll
  for (int u = 0; u < 8; ++u) {
    float4 a = *(const float4*)&Yb[i0 * 32 + u * 4];
    float4 c = *(const float4*)&Yb[(i0 + 1) * 32 + u * 4];
    y0[u * 4 + 0] = a.x; y0[u * 4 + 1] = a.y; y0[u * 4 + 2] = a.z; y0[u * 4 + 3] = a.w;
    y1[u * 4 + 0] = c.x; y1[u * 4 + 1] = c.y; y1[u * 4 + 2] = c.z; y1[u * 4 + 3] = c.w;
  }
#pragma unroll
  for (int k = 0; k < 32; ++k) {
    y0[k] = (y0[k] - (k == i0     ? p : 0.f)) * invq;
    y1[k] = (y1[k] - (k == i0 + 1 ? p : 0.f)) * invq;
  }

  // stage T1 = Yhat into Bs[0]; lane writes elements e = l*16 .. l*16+15
  {
    const int si = l >> 1, sj = (l & 1) * 16;
#pragma unroll
    for (int u = 0; u < 4; ++u) {
      const int cb0 = sj + u * 4;
      float4 a = *(const float4*)&Yb[si * 32 + cb0];
      a.x = (a.x - (si == cb0 + 0 ? p : 0.f)) * invq;
      a.y = (a.y - (si == cb0 + 1 ? p : 0.f)) * invq;
      a.z = (a.z - (si == cb0 + 2 ? p : 0.f)) * invq;
      a.w = (a.w - (si == cb0 + 3 ? p : 0.f)) * invq;
      *(float4*)&Bs[0][si * LSTR + cb0] = a;
    }
  }

  float prevt0[8], prevt1[8], curt0[8], curt1[8];
#pragma unroll
  for (int m = 0; m < 8; ++m) {
    prevt0[m] = (j0 + m == i0)     ? 1.f : 0.f;
    prevt1[m] = (j0 + m == i0 + 1) ? 1.f : 0.f;
  }

  float S[4] = {0.f, 0.f, 0.f, 0.f};

  // k = 0 term: <M_o, I>  (each diagonal element owned by exactly one lane)
#pragma unroll
  for (int o = 0; o < 4; ++o) {
    if (i0 >= j0 && i0 < j0 + 8)         S[o] += c0 * Wc[o * 1024 + i0 * 33];
    if (i0 + 1 >= j0 && i0 + 1 < j0 + 8) S[o] += c0 * Wc[o * 1024 + (i0 + 1) * 33];
  }

  __syncthreads();
  // lane's own tile of T1
#pragma unroll
  for (int u = 0; u < 2; ++u) {
    float4 a = *(const float4*)&Bs[0][i0 * LSTR + j0 + u * 4];
    float4 c = *(const float4*)&Bs[0][(i0 + 1) * LSTR + j0 + u * 4];
    curt0[u * 4 + 0] = a.x; curt0[u * 4 + 1] = a.y; curt0[u * 4 + 2] = a.z; curt0[u * 4 + 3] = a.w;
    curt1[u * 4 + 0] = c.x; curt1[u * 4 + 1] = c.y; curt1[u * 4 + 2] = c.z; curt1[u * 4 + 3] = c.w;
  }

  // contraction with lane's Wc tiles
  auto contract = [&](float coef) {
#pragma unroll
    for (int o = 0; o < 4; ++o) {
      const float* w0 = &Wc[o * 1024 + i0 * 32 + j0];
      const float* w1 = &Wc[o * 1024 + (i0 + 1) * 32 + j0];
      float ts = 0.f;
#pragma unroll
      for (int m = 0; m < 8; ++m) ts += w0[m] * curt0[m] + w1[m] * curt1[m];
      S[o] += coef * ts;
    }
  };

  contract(-2.f * rr);          // k = 1 term, c1 = -2 r

  float rk = rr;
  int cb = 0;
  for (int k = 2; k <= NCH; ++k) {
    float acc0[8], acc1[8];
#pragma unroll
    for (int m = 0; m < 8; ++m) { acc0[m] = 0.f; acc1[m] = 0.f; }
#pragma unroll
    for (int kk = 0; kk < 32; ++kk) {
      float4 bA = *(const float4*)&Bs[cb][kk * LSTR + j0];
      float4 bB = *(const float4*)&Bs[cb][kk * LSTR + j0 + 4];
      const float a0 = y0[kk], a1 = y1[kk];
      acc0[0] = fmaf(a0, bA.x, acc0[0]); acc0[1] = fmaf(a0, bA.y, acc0[1]);
      acc0[2] = fmaf(a0, bA.z, acc0[2]); acc0[3] = fmaf(a0, bA.w, acc0[3]);
      acc0[4] = fmaf(a0, bB.x, acc0[4]); acc0[5] = fmaf(a0, bB.y, acc0[5]);
      acc0[6] = fmaf(a0, bB.z, acc0[6]); acc0[7] = fmaf(a0, bB.w, acc0[7]);
      acc1[0] = fmaf(a1, bA.x, acc1[0]); acc1[1] = fmaf(a1, bA.y, acc1[1]);
      acc1[2] = fmaf(a1, bA.z, acc1[2]); acc1[3] = fmaf(a1, bA.w, acc1[3]);
      acc1[4] = fmaf(a1, bB.x, acc1[4]); acc1[5] = fmaf(a1, bB.y, acc1[5]);
      acc1[6] = fmaf(a1, bB.z, acc1[6]); acc1[7] = fmaf(a1, bB.w, acc1[7]);
    }
#pragma unroll
    for (int m = 0; m < 8; ++m) {
      const float nt0 = 2.f * acc0[m] - prevt0[m];
      const float nt1 = 2.f * acc1[m] - prevt1[m];
      prevt0[m] = curt0[m]; prevt1[m] = curt1[m];
      curt0[m] = nt0;       curt1[m] = nt1;
    }
    *(float4*)&Bs[cb ^ 1][i0 * LSTR + j0]           = make_float4(curt0[0], curt0[1], curt0[2], curt0[3]);
    *(float4*)&Bs[cb ^ 1][i0 * LSTR + j0 + 4]       = make_float4(curt0[4], curt0[5], curt0[6], curt0[7]);
    *(float4*)&Bs[cb ^ 1][(i0 + 1) * LSTR + j0]     = make_float4(curt1[0], curt1[1], curt1[2], curt1[3]);
    *(float4*)&Bs[cb ^ 1][(i0 + 1) * LSTR + j0 + 4] = make_float4(curt1[4], curt1[5], curt1[6], curt1[7]);
    __syncthreads();
    cb ^= 1;
    rk *= rr;
    contract(-2.f * rk / (float)k);
  }

  // reduce S over 64 lanes
#pragma unroll
  for (int off = 32; off >= 1; off >>= 1) {
    S[0] += __shfl_xor(S[0], off);
    S[1] += __shfl_xor(S[1], off);
    S[2] += __shfl_xor(S[2], off);
    S[3] += __shfl_xor(S[3], off);
  }

  if (l == 0) {
    const float lg0 = S[0] + bcv[0];
    const float lg1 = S[1] + bcv[1];
    const float lg2 = S[2] + bcv[2];
    const float lg3 = S[3] + bcv[3];
    const float mx = fmaxf(fmaxf(lg0, lg1), fmaxf(lg2, lg3));
    const float se = expf(lg0 - mx) + expf(lg1 - mx) + expf(lg2 - mx) + expf(lg3 - mx);
    const float lse = mx + logf(se);
    *(float4*)&out[(size_t)b * 4] =
        make_float4(lg0 - lse, lg1 - lse, lg2 - lse, lg3 - lse);
  }
}

extern "C" void kernel_launch(void* const* d_in, const int* in_sizes, int n_in,
                              void* d_out, int out_size, void* d_ws, size_t ws_size,
                              hipStream_t stream)
{
  const float* x  = (const float*)d_in[0];
  const float* W  = (const float*)d_in[1];
  const float* Wc = (const float*)d_in[2];
  const float* bc = (const float*)d_in[3];
  float* out = (float*)d_out;
  float* Y   = (float*)d_ws;          // 4096*1024 floats = 16.8 MB scratch

  const int nB = in_sizes[0] / (C_CH * T_LEN);   // 4096

  spd_stage1<<<nB, 256, 0, stream>>>(x, W, Y);
  spd_cheb<<<nB, 64, 0, stream>>>(Y, Wc, bc, out);
}

// Round 2
// 117.702 us; speedup vs baseline: 3.6930x; 3.6930x over previous
//
#include <hip/hip_runtime.h>
#include <math.h>

// SPDNet fused: x[4096,64,256] --(bf16-split MFMA)--> V^T = x^T W
//   --> Y = V V^T/T - m m^T  (32x32 SPD, C-layout regs)
//   --> log(Y) via Chebyshev matrix recurrence on MFMA (in-register,
//       C->B frag conversion via permlane32_swap; no LDS anywhere)
//   --> <Wc_o, log(Y)> + bc --> log_softmax --> out.
// One wave per sample; 4 waves per block; zero LDS, zero global scratch.

typedef __attribute__((ext_vector_type(8))) short short8;   // bf16x8 frag (4 VGPR)
typedef __attribute__((ext_vector_type(16))) float f32x16;  // MFMA C/D

#define NCH 22

__device__ inline unsigned pkbf(float a, float b) {
  // packed truncated-bf16 pair: low16 = bf16(a), high16 = bf16(b)
  return (__builtin_bit_cast(unsigned, a) >> 16) |
         (__builtin_bit_cast(unsigned, b) & 0xffff0000u);
}
__device__ inline float bf_hi_f(float f) {
  // value of truncated bf16(f) as float (residual = f - bf_hi_f(f), exact)
  return __builtin_bit_cast(float, __builtin_bit_cast(unsigned, f) & 0xffff0000u);
}

// C-layout (lane holds col=l&31, rows (m&3)+8*(m>>2)+4*(l>>5)) -> B-frag pairs
// for the two K=16 slices, hi/lo bf16 split. B-frag: lane holds
// M[ks*16 + 8*(l>>5) + jj][l&31], jj=0..7 (also serves as A-frag of M^T).
__device__ inline void c2frags(const float* c, short8& h0, short8& l0,
                               short8& h1, short8& l1) {
  unsigned ph[8], pl[8];
#pragma unroll
  for (int w = 0; w < 8; ++w) {
    const float a = c[2 * w], b = c[2 * w + 1];
    ph[w] = pkbf(a, b);
    pl[w] = pkbf(a - bf_hi_f(a), b - bf_hi_f(b));
  }
  union { unsigned u[4]; short8 s; } H0, L0, H1, L1;
  {
    auto r = __builtin_amdgcn_permlane32_swap((int)ph[0], (int)ph[2], false, false);
    H0.u[0] = (unsigned)r[0]; H0.u[2] = (unsigned)r[1];
    r = __builtin_amdgcn_permlane32_swap((int)ph[1], (int)ph[3], false, false);
    H0.u[1] = (unsigned)r[0]; H0.u[3] = (unsigned)r[1];
    r = __builtin_amdgcn_permlane32_swap((int)ph[4], (int)ph[6], false, false);
    H1.u[0] = (unsigned)r[0]; H1.u[2] = (unsigned)r[1];
    r = __builtin_amdgcn_permlane32_swap((int)ph[5], (int)ph[7], false, false);
    H1.u[1] = (unsigned)r[0]; H1.u[3] = (unsigned)r[1];
    r = __builtin_amdgcn_permlane32_swap((int)pl[0], (int)pl[2], false, false);
    L0.u[0] = (unsigned)r[0]; L0.u[2] = (unsigned)r[1];
    r = __builtin_amdgcn_permlane32_swap((int)pl[1], (int)pl[3], false, false);
    L0.u[1] = (unsigned)r[0]; L0.u[3] = (unsigned)r[1];
    r = __builtin_amdgcn_permlane32_swap((int)pl[4], (int)pl[6], false, false);
    L1.u[0] = (unsigned)r[0]; L1.u[2] = (unsigned)r[1];
    r = __builtin_amdgcn_permlane32_swap((int)pl[5], (int)pl[7], false, false);
    L1.u[1] = (unsigned)r[0]; L1.u[3] = (unsigned)r[1];
  }
  h0 = H0.s; l0 = L0.s; h1 = H1.s; l1 = L1.s;
}

__device__ inline f32x16 mfma_bf16(short8 a, short8 b, f32x16 c) {
  return __builtin_amdgcn_mfma_f32_32x32x16_bf16(a, b, c, 0, 0, 0);
}

__global__ __launch_bounds__(256) void spd_fused(
    const float* __restrict__ x, const float* __restrict__ W,
    const float* __restrict__ Wc, const float* __restrict__ bcv,
    float* __restrict__ out, int nB)
{
  const int wv = threadIdx.x >> 6;
  const int l  = threadIdx.x & 63;
  const int b  = blockIdx.x * 4 + wv;
  if (b >= nB) return;
  const int half = l >> 5, col = l & 31;

  // ---- W as B-frags (K-slices of 16 over C=64), hi/lo split ----
  short8 wh[4], wl[4];
#pragma unroll
  for (int cs = 0; cs < 4; ++cs) {
    float wr[8];
#pragma unroll
    for (int j = 0; j < 8; ++j)
      wr[j] = W[(cs * 16 + 8 * half + j) * 32 + col];
    union { unsigned u[4]; short8 s; } Hh, Ll;
#pragma unroll
    for (int w = 0; w < 4; ++w) {
      const float a = wr[2 * w], bq = wr[2 * w + 1];
      Hh.u[w] = pkbf(a, bq);
      Ll.u[w] = pkbf(a - bf_hi_f(a), bq - bf_hi_f(bq));
    }
    wh[cs] = Hh.s; wl[cs] = Ll.s;
  }

  // ---- stream x: Vtb = x_tb^T W (MFMA), Y += Vtb^T Vtb (MFMA) ----
  const float* xb = x + (size_t)b * (64 * 256);
  f32x16 Yac = {0.f,0.f,0.f,0.f,0.f,0.f,0.f,0.f,0.f,0.f,0.f,0.f,0.f,0.f,0.f,0.f};
  float macc = 0.f;

#pragma unroll 2
  for (int tb = 0; tb < 8; ++tb) {
    short8 xh[4], xl[4];
#pragma unroll
    for (int cs = 0; cs < 4; ++cs) {
      float xr[8];
#pragma unroll
      for (int j = 0; j < 8; ++j)
        xr[j] = xb[(cs * 16 + 8 * half + j) * 256 + tb * 32 + col];
      union { unsigned u[4]; short8 s; } Hh, Ll;
#pragma unroll
      for (int w = 0; w < 4; ++w) {
        const float a = xr[2 * w], bq = xr[2 * w + 1];
        Hh.u[w] = pkbf(a, bq);
        Ll.u[w] = pkbf(a - bf_hi_f(a), bq - bf_hi_f(bq));
      }
      xh[cs] = Hh.s; xl[cs] = Ll.s;
    }
    f32x16 V = {0.f,0.f,0.f,0.f,0.f,0.f,0.f,0.f,0.f,0.f,0.f,0.f,0.f,0.f,0.f,0.f};
#pragma unroll
    for (int cs = 0; cs < 4; ++cs) {
      V = mfma_bf16(xh[cs], wh[cs], V);
      V = mfma_bf16(xh[cs], wl[cs], V);
      V = mfma_bf16(xl[cs], wh[cs], V);
    }
    // accumulate column sums (per-lane col d = col): rows are t-indices
    float vv[16];
#pragma unroll
    for (int m = 0; m < 16; ++m) { vv[m] = V[m]; macc += vv[m]; }
    // C->frag conversion; frags serve as both A (of Vt^T) and B (of Vt)
    short8 bh0, bl0, bh1, bl1;
    c2frags(vv, bh0, bl0, bh1, bl1);
    Yac = mfma_bf16(bh0, bh0, Yac);
    Yac = mfma_bf16(bh0, bl0, Yac);
    Yac = mfma_bf16(bl0, bh0, Yac);
    Yac = mfma_bf16(bh1, bh1, Yac);
    Yac = mfma_bf16(bh1, bl1, Yac);
    Yac = mfma_bf16(bl1, bh1, Yac);
  }

  // ---- means, normalize: Yhat = (Y/256 - m m^T - p I)/q ----
  macc += __shfl_xor(macc, 32);
  const float msn = macc * (1.f / 256.f);     // m_d for d = col (all lanes)

  const float lo = 0.08f, hi = 3.0f;
  const float p = 0.5f * (hi + lo), q = 0.5f * (hi - lo), invq = 1.f / q;
  const float rr = -(p - sqrtf(lo * hi)) * invq;   // ~ -0.719
  const float c0 = logf(p / (1.f + rr * rr));

  float Tc[16], Tp[16], G[16];
#pragma unroll
  for (int m = 0; m < 16; ++m) {
    const int r = (m & 3) + 8 * (m >> 2) + 4 * half;
    const float mrow = __shfl(msn, r);
    const float yv = Yac[m] * (1.f / 256.f) - mrow * msn;
    const float yn = (yv - (r == col ? p : 0.f)) * invq;
    const float id = (r == col) ? 1.f : 0.f;
    Tc[m] = yn; Tp[m] = id;
    G[m] = c0 * id + (-2.f * rr) * yn;
  }

  // A-frags of symmetric Yhat (conversion output = A-frag of M^T = A of M)
  short8 ah0, al0, ah1, al1;
  c2frags(Tc, ah0, al0, ah1, al1);

  // ---- Chebyshev recurrence: T_new = 2 Yhat T - T_prev ----
  float rk = rr;
  for (int k = 2; k <= NCH; ++k) {
    short8 bh0, bl0, bh1, bl1;
    c2frags(Tc, bh0, bl0, bh1, bl1);
    f32x16 P = {0.f,0.f,0.f,0.f,0.f,0.f,0.f,0.f,0.f,0.f,0.f,0.f,0.f,0.f,0.f,0.f};
    P = mfma_bf16(ah0, bh0, P);
    P = mfma_bf16(ah1, bh1, P);
    P = mfma_bf16(ah0, bl0, P);
    P = mfma_bf16(ah1, bl1, P);
    P = mfma_bf16(al0, bh0, P);
    P = mfma_bf16(al1, bh1, P);
    rk *= rr;
    const float ck = -2.f * rk / (float)k;
#pragma unroll
    for (int m = 0; m < 16; ++m) {
      const float tn = 2.f * P[m] - Tp[m];
      Tp[m] = Tc[m]; Tc[m] = tn;
      G[m] = fmaf(ck, tn, G[m]);
    }
  }

  // ---- logits: S_o = <Wc_o, G>, wave-reduce, log_softmax ----
  float S[4];
#pragma unroll
  for (int o = 0; o < 4; ++o) {
    float s = 0.f;
#pragma unroll
    for (int m = 0; m < 16; ++m) {
      const int r = (m & 3) + 8 * (m >> 2) + 4 * half;
      s = fmaf(Wc[o * 1024 + r * 32 + col], G[m], s);
    }
    S[o] = s;
  }
#pragma unroll
  for (int off = 32; off >= 1; off >>= 1) {
    S[0] += __shfl_xor(S[0], off);
    S[1] += __shfl_xor(S[1], off);
    S[2] += __shfl_xor(S[2], off);
    S[3] += __shfl_xor(S[3], off);
  }
  if (l == 0) {
    const float lg0 = S[0] + bcv[0];
    const float lg1 = S[1] + bcv[1];
    const float lg2 = S[2] + bcv[2];
    const float lg3 = S[3] + bcv[3];
    const float mx = fmaxf(fmaxf(lg0, lg1), fmaxf(lg2, lg3));
    const float se = expf(lg0 - mx) + expf(lg1 - mx) +
                     expf(lg2 - mx) + expf(lg3 - mx);
    const float lse = mx + logf(se);
    *(float4*)&out[(size_t)b * 4] =
        make_float4(lg0 - lse, lg1 - lse, lg2 - lse, lg3 - lse);
  }
}

extern "C" void kernel_launch(void* const* d_in, const int* in_sizes, int n_in,
                              void* d_out, int out_size, void* d_ws, size_t ws_size,
                              hipStream_t stream)
{
  const float* x  = (const float*)d_in[0];
  const float* W  = (const float*)d_in[1];
  const float* Wc = (const float*)d_in[2];
  const float* bc = (const float*)d_in[3];
  float* out = (float*)d_out;

  const int nB = in_sizes[0] / (64 * 256);   // 4096
  const int blocks = (nB + 3) / 4;

  spd_fused<<<blocks, 256, 0, stream>>>(x, W, Wc, bc, out, nB);
}